// Round 4
// baseline (288.279 us; speedup 1.0000x reference)
//
#include <hip/hip_runtime.h>
#include <math.h>

#define E_ 8
#define H_ 256
#define N_ 65536
#define NHID_ 3
#define MT 64          // tile: N/64 = 1024 exact
#define HPAD 264       // LDS row stride (bf16 elems): row stride 528B
#define OMEGA_ 30.0f
#define REV_SCALE 4.7746482927568605f   // OMEGA/(2*pi): sin(OMEGA*z) = sin(2pi*(REV_SCALE*z))

// R22 = R21 + XOR column swizzle on h_hi to kill the epilogue's 4-way bank
// conflict (13.6M conflict-cycles ~= 22us of LDS-pipe serialization).
// Physical col = logical col ^ (((row>>3)&1)<<4). Rows r and r+8 share banks
// (8*528B == 0 mod 128B); the XOR shifts the +8-row quad by 8 dwords, giving
// quads bank groups {+0,+16,+8,+24} -> 32 banks, 2 lanes/bank = conflict-free.
// XOR bit is THREAD-CONSTANT in every pattern (epilogue: quad>>1; A/out reads:
// (l15>>3)&1; first layer: scalar per m) -> folds into base addrs, zero VALU.
// Values bit-identical -> absmax unchanged.
// ws layout: Pwh_hi | Pwo_hi | Pwo_lo
#define PWH_ELEMS (E_ * NHID_ * 8 * 16 * 64 * 8)   // 1572864 bf16 = 3145728 B
#define PWO_ELEMS (E_ * 8 * 64 * 8)                // 32768 bf16 = 65536 B
#define WS_NEEDED ((size_t)PWH_ELEMS * 2 + 2 * (size_t)PWO_ELEMS * 2)  // 3276800 B

typedef __attribute__((ext_vector_type(8))) __bf16 bf16x8;
typedef __attribute__((ext_vector_type(4))) float f32x4;

// RNE split (pack + fallback path)
__device__ __forceinline__ void split_bf16(float v, __bf16& hi, __bf16& lo) {
  hi = (__bf16)v;
  lo = (__bf16)(v - (float)hi);
}

// hot-path: sin + RNE-bf16 + single LDS store. NO fract: inputs bounded |z|<=8.2
// revolutions, inside v_sin_f32's valid +-256 range (HW reduces internally).
__device__ __forceinline__ void sin_store(float z_rev, __bf16* h_hi, int idx) {
  const float s = __builtin_amdgcn_sinf(z_rev);   // sin(2*pi*z_rev)
  h_hi[idx] = (__bf16)s;   // RNE
}

// ---- zero d_out (fallback path only) ----
__global__ void zero_out_k(float* __restrict__ out) {
  out[blockIdx.x * 256 + threadIdx.x] = 0.0f;   // grid exactly N_*3/256
}

// ---- fused prep: zero out + pack Wh*REV_SCALE (hi only) + pack Wout (hi/lo) ----
// grid 768 x 256 = 196608 threads = N_*3 exactly (zeroing) = Wh frag count.
// Wh 16x16x32 B-frag order: value(t,j) = REV*Wh[el][kb*32+quad*8+j][nb*16+l15]
__global__ void prep_k(const float* __restrict__ Wh,
                       const float* __restrict__ Wout,
                       __bf16* __restrict__ Pwh,
                       __bf16* __restrict__ Pwo_hi,
                       __bf16* __restrict__ Pwo_lo,
                       float* __restrict__ out) {
  const int t = blockIdx.x * 256 + threadIdx.x;
  out[t] = 0.0f;                                  // N_*3 == 196608 == grid*block
  const int lane = t & 63;
  const int r = t >> 6;            // [0, 3072)
  const int nb = r & 15;
  const int kb = (r >> 4) & 7;
  const int el = r >> 7;           // [0, 24) = e*3+l
  const int n  = nb * 16 + (lane & 15);
  const int k0 = kb * 32 + (lane >> 4) * 8;
  const float* src = Wh + (size_t)el * (H_ * H_);
  __bf16* dhi = Pwh + (size_t)t * 8;
#pragma unroll
  for (int j = 0; j < 8; ++j)
    dhi[j] = (__bf16)(src[(size_t)(k0 + j) * H_ + n] * REV_SCALE);

  // Wout pack (UNscaled — final layer linear), 16x16x32 layout, t < 4096
  if (t < E_ * 8 * 64) {
    const int kb2 = (t >> 6) & 7;
    const int e   = t >> 9;
    const int n2  = lane & 15;
    const int k02 = kb2 * 32 + (lane >> 4) * 8;
    __bf16* dh = Pwo_hi + (size_t)t * 8;
    __bf16* dl = Pwo_lo + (size_t)t * 8;
#pragma unroll
    for (int j = 0; j < 8; ++j) {
      float v = (n2 < 3) ? Wout[((size_t)e * H_ + (k02 + j)) * 3 + n2] : 0.0f;
      __bf16 hi, lo;
      split_bf16(v, hi, lo);
      dh[j] = hi; dl[j] = lo;
    }
  }
}

// ---- fused MoE-SIREN, PACKED path, MT=64, single-MFMA hidden layers ----
// R18 structure (best verified: 231us), minus fract (R21), plus h_hi XOR swizzle.
__global__ __launch_bounds__(256, 4) void moe_main_packed_k(
    const float* __restrict__ x,
    const float* __restrict__ gate_W,
    const float* __restrict__ gate_b,
    const float* __restrict__ W0,
    const float* __restrict__ b0,
    const __bf16* __restrict__ Pwh_hi,
    const float* __restrict__ bh,
    const __bf16* __restrict__ Pwo_hi,
    const __bf16* __restrict__ Pwo_lo,
    const float* __restrict__ bout,
    float* __restrict__ out)
{
  __shared__ alignas(16) __bf16 h_hi[MT * HPAD];   // 33792 B
  __shared__ float gate_s[MT];                     // total ~34 KB -> 4 blocks/CU

  const int e    = blockIdx.y;
  const int m0   = blockIdx.x * MT;
  const int tid  = threadIdx.x;
  const int wave = tid >> 6;
  const int lane = tid & 63;
  const int l15  = lane & 15;
  const int quad = lane >> 4;
  const int kxor = ((l15 >> 3) & 1) << 4;   // read-side swizzle (rows ·16+l15)
  const int nxor = (quad >> 1) << 4;        // epilogue write-side swizzle

  // gate for this expert, one row per thread (fp32, matches jax softmax)
  if (tid < MT) {
    const int mg = m0 + tid;
    const float x0 = x[mg * 2 + 0];
    const float x1 = x[mg * 2 + 1];
    float lg[E_];
    float mx = -1e30f;
#pragma unroll
    for (int k = 0; k < E_; ++k) {
      lg[k] = x0 * gate_W[k] + x1 * gate_W[E_ + k] + gate_b[k];
      mx = fmaxf(mx, lg[k]);
    }
    float s = 0.0f;
#pragma unroll
    for (int k = 0; k < E_; ++k) s += __expf(lg[k] - mx);
    gate_s[tid] = __expf(lg[e] - mx) / s;
  }

  // first sine layer fp32, omega/2pi folded; thread tid owns column n=tid, all 64
  // rows. Swizzle: physical col = tid ^ (((m>>3)&1)<<4) — scalar select per m.
  {
    const float w0a = W0[(e * 2 + 0) * H_ + tid] * REV_SCALE;
    const float w1a = W0[(e * 2 + 1) * H_ + tid] * REV_SCALE;
    const float bb  = b0[e * H_ + tid] * REV_SCALE;
    for (int m = 0; m < MT; ++m) {
      const float x0 = x[(m0 + m) * 2 + 0];
      const float x1 = x[(m0 + m) * 2 + 1];
      const float z_rev = fmaf(x1, w1a, fmaf(x0, w0a, bb));
      const int colm = tid ^ (((m >> 3) & 1) << 4);
      sin_store(z_rev, h_hi, m * HPAD + colm);
    }
  }
  __syncthreads();

  const int nb0 = wave * 4;
  const size_t fragoff = (size_t)(nb0 * 64 + lane) * 8;   // wave-invariant frag offset

#pragma unroll 1
  for (int l = 0; l < NHID_; ++l) {
    const size_t lbase = (size_t)(e * NHID_ + l) * (8 * 16 * 64 * 8);
    const __bf16* pBh = Pwh_hi + lbase + fragoff;
    const float* bhrow = bh + (size_t)(e * NHID_ + l) * H_;

    // bias folded into acc init (C/D col = lane-only -> one bias per nbi, all 16 regs)
    float bias_rev[4];
#pragma unroll
    for (int nbi = 0; nbi < 4; ++nbi)
      bias_rev[nbi] = bhrow[(nb0 + nbi) * 16 + l15] * REV_SCALE;

    f32x4 acc[4][4];
#pragma unroll
    for (int mt = 0; mt < 4; ++mt)
#pragma unroll
      for (int nbi = 0; nbi < 4; ++nbi)
        acc[mt][nbi] = (f32x4){bias_rev[nbi], bias_rev[nbi], bias_rev[nbi], bias_rev[nbi]};

#pragma unroll 1          // ONE kb in flight: VGPR discipline
    for (int kb = 0; kb < 8; ++kb) {
      bf16x8 bhf[4];
#pragma unroll
      for (int nbi = 0; nbi < 4; ++nbi)
        bhf[nbi] = *reinterpret_cast<const bf16x8*>(pBh + nbi * 512);
      pBh += 16 * 64 * 8;   // 8192 elems per kb
      const int k0 = (kb * 32 + quad * 8) ^ kxor;   // 8-aligned, bit4 const over run
      bf16x8 ah[4];
#pragma unroll
      for (int mt = 0; mt < 4; ++mt)
        ah[mt] = *reinterpret_cast<const bf16x8*>(&h_hi[(mt * 16 + l15) * HPAD + k0]);
#pragma unroll
      for (int mt = 0; mt < 4; ++mt)
#pragma unroll
        for (int nbi = 0; nbi < 4; ++nbi)
          acc[mt][nbi] = __builtin_amdgcn_mfma_f32_16x16x32_bf16(
              ah[mt], bhf[nbi], acc[mt][nbi], 0, 0, 0);
    }
    __syncthreads();

    // epilogue: physical col = n ^ nxor (nxor = quad>>1 <<4). Per store inst the
    // four quads land on dword-bank groups {+0,+16,+8,+24} -> conflict-free.
#pragma unroll
    for (int nbi = 0; nbi < 4; ++nbi) {
      const int n = ((nb0 + nbi) * 16 + l15) ^ nxor;
#pragma unroll
      for (int mt = 0; mt < 4; ++mt) {
        const int rbase = mt * 16 + quad * 4;
#pragma unroll
        for (int i = 0; i < 4; ++i)
          sin_store(acc[mt][nbi][i], h_hi, (rbase + i) * HPAD + n);
      }
    }
    __syncthreads();
  }

  // output layer (linear): 2-term kept (only 16 MFMAs/wave — free accuracy)
  {
    const __bf16* pOh = Pwo_hi + (size_t)e * (8 * 64 * 8) + (size_t)lane * 8;
    const __bf16* pOl = Pwo_lo + (size_t)e * (8 * 64 * 8) + (size_t)lane * 8;
    f32x4 acco = (f32x4){0.f, 0.f, 0.f, 0.f};
    const int arow = wave * 16 + l15;
#pragma unroll 1
    for (int kb = 0; kb < 8; ++kb) {
      bf16x8 bhf = *reinterpret_cast<const bf16x8*>(pOh);
      bf16x8 blf = *reinterpret_cast<const bf16x8*>(pOl);
      pOh += 512; pOl += 512;
      const int k0 = (kb * 32 + quad * 8) ^ kxor;
      bf16x8 ah = *reinterpret_cast<const bf16x8*>(&h_hi[arow * HPAD + k0]);
      acco = __builtin_amdgcn_mfma_f32_16x16x32_bf16(ah, blf, acco, 0, 0, 0);
      acco = __builtin_amdgcn_mfma_f32_16x16x32_bf16(ah, bhf, acco, 0, 0, 0);
    }
    if (l15 < 3) {
      const float bo = bout[e * 3 + l15];
      const int rb = wave * 16 + quad * 4;
#pragma unroll
      for (int i = 0; i < 4; ++i) {
        const int m = rb + i;
        const float val = gate_s[m] * (acco[i] + bo);
        atomicAdd(&out[(size_t)(m0 + m) * 3 + l15], val);
      }
    }
  }
}

// ---- fallback: direct fp32-weight path (HW-verified round 3, MT=64, 3-term) ----
__global__ __launch_bounds__(256) void moe_main_direct_k(
    const float* __restrict__ x,
    const float* __restrict__ gate_W,
    const float* __restrict__ gate_b,
    const float* __restrict__ W0,
    const float* __restrict__ b0,
    const float* __restrict__ Wh,
    const float* __restrict__ bh,
    const float* __restrict__ Wout,
    const float* __restrict__ bout,
    float* __restrict__ out)
{
  __shared__ alignas(16) __bf16 h_hi[MT * HPAD];
  __shared__ alignas(16) __bf16 h_lo[MT * HPAD];
  __shared__ float gate_s[MT];

  const int e    = blockIdx.y;
  const int m0   = blockIdx.x * MT;
  const int tid  = threadIdx.x;
  const int wave = tid >> 6;
  const int lane = tid & 63;
  const int l15  = lane & 15;
  const int quad = lane >> 4;

  if (tid < MT) {
    const int mg = m0 + tid;
    const float x0 = x[mg * 2 + 0];
    const float x1 = x[mg * 2 + 1];
    float lg[E_];
    float mx = -1e30f;
#pragma unroll
    for (int k = 0; k < E_; ++k) {
      lg[k] = x0 * gate_W[k] + x1 * gate_W[E_ + k] + gate_b[k];
      mx = fmaxf(mx, lg[k]);
    }
    float s = 0.0f;
#pragma unroll
    for (int k = 0; k < E_; ++k) s += __expf(lg[k] - mx);
    gate_s[tid] = __expf(lg[e] - mx) / s;
  }
  {
    const float w0a = W0[(e * 2 + 0) * H_ + tid];
    const float w1a = W0[(e * 2 + 1) * H_ + tid];
    const float bb  = b0[e * H_ + tid];
    for (int m = 0; m < MT; ++m) {
      const float x0 = x[(m0 + m) * 2 + 0];
      const float x1 = x[(m0 + m) * 2 + 1];
      const float z = OMEGA_ * fmaf(x1, w1a, fmaf(x0, w0a, bb));
      const float h = __sinf(z);
      __bf16 hi, lo; split_bf16(h, hi, lo);
      h_hi[m * HPAD + tid] = hi;
      h_lo[m * HPAD + tid] = lo;
    }
  }
  __syncthreads();

  const int nb0 = wave * 4;
#pragma unroll 1
  for (int l = 0; l < NHID_; ++l) {
    const float* WB = Wh + (size_t)(e * NHID_ + l) * (H_ * H_);
    f32x4 acc[4][4];
#pragma unroll
    for (int mt = 0; mt < 4; ++mt)
#pragma unroll
      for (int nbi = 0; nbi < 4; ++nbi)
        acc[mt][nbi] = (f32x4){0.f, 0.f, 0.f, 0.f};

#pragma unroll 2
    for (int kb = 0; kb < 8; ++kb) {
      const int k0 = kb * 32 + quad * 8;
      float bfv[4][8];
#pragma unroll
      for (int nbi = 0; nbi < 4; ++nbi) {
        const float* p = WB + (size_t)k0 * H_ + (nb0 + nbi) * 16 + l15;
#pragma unroll
        for (int j = 0; j < 8; ++j) bfv[nbi][j] = p[(size_t)j * H_];
      }
      bf16x8 ah[4], al[4];
#pragma unroll
      for (int mt = 0; mt < 4; ++mt) {
        ah[mt] = *reinterpret_cast<const bf16x8*>(&h_hi[(mt * 16 + l15) * HPAD + k0]);
        al[mt] = *reinterpret_cast<const bf16x8*>(&h_lo[(mt * 16 + l15) * HPAD + k0]);
      }
      bf16x8 bhf[4], blf[4];
#pragma unroll
      for (int nbi = 0; nbi < 4; ++nbi)
#pragma unroll
        for (int j = 0; j < 8; ++j) {
          __bf16 hi, lo; split_bf16(bfv[nbi][j], hi, lo);
          bhf[nbi][j] = hi; blf[nbi][j] = lo;
        }
#pragma unroll
      for (int mt = 0; mt < 4; ++mt)
#pragma unroll
        for (int nbi = 0; nbi < 4; ++nbi) {
          f32x4 a = acc[mt][nbi];
          a = __builtin_amdgcn_mfma_f32_16x16x32_bf16(al[mt], bhf[nbi], a, 0, 0, 0);
          a = __builtin_amdgcn_mfma_f32_16x16x32_bf16(ah[mt], blf[nbi], a, 0, 0, 0);
          a = __builtin_amdgcn_mfma_f32_16x16x32_bf16(ah[mt], bhf[nbi], a, 0, 0, 0);
          acc[mt][nbi] = a;
        }
    }
    __syncthreads();

    const float* bhrow = bh + (size_t)(e * NHID_ + l) * H_;
#pragma unroll
    for (int nbi = 0; nbi < 4; ++nbi) {
      const int n = (nb0 + nbi) * 16 + l15;
      const float bias = bhrow[n];
#pragma unroll
      for (int mt = 0; mt < 4; ++mt) {
        const int rbase = mt * 16 + quad * 4;
#pragma unroll
        for (int i = 0; i < 4; ++i) {
          const float z = OMEGA_ * (acc[mt][nbi][i] + bias);
          const float h = __sinf(z);
          __bf16 hi, lo; split_bf16(h, hi, lo);
          h_hi[(rbase + i) * HPAD + n] = hi;
          h_lo[(rbase + i) * HPAD + n] = lo;
        }
      }
    }
    __syncthreads();
  }

  {
    const float* WO = Wout + (size_t)e * (H_ * 3);
    f32x4 acco = (f32x4){0.f, 0.f, 0.f, 0.f};
    const int arow = wave * 16 + l15;
#pragma unroll
    for (int kb = 0; kb < 8; ++kb) {
      const int k0 = kb * 32 + quad * 8;
      float bfv[8];
#pragma unroll
      for (int j = 0; j < 8; ++j)
        bfv[j] = (l15 < 3) ? WO[(size_t)(k0 + j) * 3 + l15] : 0.0f;
      bf16x8 ah = *reinterpret_cast<const bf16x8*>(&h_hi[arow * HPAD + k0]);
      bf16x8 al = *reinterpret_cast<const bf16x8*>(&h_lo[arow * HPAD + k0]);
      bf16x8 bhf, blf;
#pragma unroll
      for (int j = 0; j < 8; ++j) {
        __bf16 hi, lo; split_bf16(bfv[j], hi, lo);
        bhf[j] = hi; blf[j] = lo;
      }
      acco = __builtin_amdgcn_mfma_f32_16x16x32_bf16(al, bhf, acco, 0, 0, 0);
      acco = __builtin_amdgcn_mfma_f32_16x16x32_bf16(ah, blf, acco, 0, 0, 0);
      acco = __builtin_amdgcn_mfma_f32_16x16x32_bf16(ah, bhf, acco, 0, 0, 0);
    }
    if (l15 < 3) {
      const float bo = bout[e * 3 + l15];
      const int rb = wave * 16 + quad * 4;
#pragma unroll
      for (int i = 0; i < 4; ++i) {
        const int m = rb + i;
        const float val = gate_s[m] * (acco[i] + bo);
        atomicAdd(&out[(size_t)(m0 + m) * 3 + l15], val);
      }
    }
  }
}

extern "C" void kernel_launch(void* const* d_in, const int* in_sizes, int n_in,
                              void* d_out, int out_size, void* d_ws, size_t ws_size,
                              hipStream_t stream) {
  const float* x     = (const float*)d_in[0];
  const float* gateW = (const float*)d_in[1];
  const float* gateb = (const float*)d_in[2];
  const float* W0    = (const float*)d_in[3];
  const float* b0    = (const float*)d_in[4];
  const float* Wh    = (const float*)d_in[5];
  const float* bh    = (const float*)d_in[6];
  const float* Wout  = (const float*)d_in[7];
  const float* bout  = (const float*)d_in[8];
  float* out = (float*)d_out;

  if (ws_size >= WS_NEEDED) {
    __bf16* Pwh_hi = (__bf16*)d_ws;
    __bf16* Pwo_hi = (__bf16*)((char*)d_ws + (size_t)PWH_ELEMS * 2);
    __bf16* Pwo_lo = (__bf16*)((char*)d_ws + (size_t)PWH_ELEMS * 2 + (size_t)PWO_ELEMS * 2);
    hipLaunchKernelGGL(prep_k, dim3(768), dim3(256), 0, stream,
                       Wh, Wout, Pwh_hi, Pwo_hi, Pwo_lo, out);
    hipLaunchKernelGGL(moe_main_packed_k, dim3(N_ / MT, E_), dim3(256), 0, stream,
                       x, gateW, gateb, W0, b0, Pwh_hi, bh, Pwo_hi, Pwo_lo, bout, out);
  } else {
    hipLaunchKernelGGL(zero_out_k, dim3(N_ * 3 / 256), dim3(256), 0, stream, out);
    hipLaunchKernelGGL(moe_main_direct_k, dim3(N_ / MT, E_), dim3(256), 0, stream,
                       x, gateW, gateb, W0, b0, Wh, bh, Wout, bout, out);
  }
}

// Round 5
// 280.624 us; speedup vs baseline: 1.0273x; 1.0273x over previous
//
#include <hip/hip_runtime.h>
#include <math.h>

#define E_ 8
#define H_ 256
#define N_ 65536
#define NHID_ 3
#define MT 64          // tile: N/64 = 1024 exact
#define HPAD 264       // LDS row stride (bf16 elems): row stride 528B
#define OMEGA_ 30.0f
#define REV_SCALE 4.7746482927568605f   // OMEGA/(2*pi): sin(OMEGA*z) = sin(2pi*(REV_SCALE*z))

// R23 = R21 + 2-deep register ping-pong prefetch of B-fragments.
// R22 post-mortem: epilogue XOR swizzle provably changed the LDS layout but
// SQ_LDS_BANK_CONFLICT stayed exactly 1.363e7 and dur was flat -> the conflict
// counter is NOT the epilogue stores and is not wall-time; swizzle dropped.
// Remaining GEMM-phase inefficiency theory: unroll-1 kb loop exposes B-frag
// L2 latency (~200cy, 3.1GB total through L2) once per kb. Pipeline:
//   - bB(kb+1) issued before MFMA-block(kb)
//   - bA(kb+2) issued between the two MFMA half-blocks
//   - ACROSS LAYERS: bA(layer l+1, kb0) issued before the epilogue barrier
//     (global load, no LDS dependency -> legally crosses __syncthreads; the
//     whole VALU epilogue hides it). Layers are contiguous in Pwh so the
//     running pointer needs no recompute.
// +16 VGPR (bB), no numeric change (absmax bit-identical).
// ws layout: Pwh_hi | Pwo_hi | Pwo_lo
#define PWH_ELEMS (E_ * NHID_ * 8 * 16 * 64 * 8)   // 1572864 bf16 = 3145728 B
#define PWO_ELEMS (E_ * 8 * 64 * 8)                // 32768 bf16 = 65536 B
#define WS_NEEDED ((size_t)PWH_ELEMS * 2 + 2 * (size_t)PWO_ELEMS * 2)  // 3276800 B

typedef __attribute__((ext_vector_type(8))) __bf16 bf16x8;
typedef __attribute__((ext_vector_type(4))) float f32x4;

// RNE split (pack + fallback path)
__device__ __forceinline__ void split_bf16(float v, __bf16& hi, __bf16& lo) {
  hi = (__bf16)v;
  lo = (__bf16)(v - (float)hi);
}

// hot-path: sin + RNE-bf16 + single LDS store. NO fract: inputs bounded |z|<=8.2
// revolutions, inside v_sin_f32's valid +-256 range (HW reduces internally).
__device__ __forceinline__ void sin_store(float z_rev, __bf16* h_hi, int idx) {
  const float s = __builtin_amdgcn_sinf(z_rev);   // sin(2*pi*z_rev)
  h_hi[idx] = (__bf16)s;   // RNE
}

// ---- zero d_out (fallback path only) ----
__global__ void zero_out_k(float* __restrict__ out) {
  out[blockIdx.x * 256 + threadIdx.x] = 0.0f;   // grid exactly N_*3/256
}

// ---- fused prep: zero out + pack Wh*REV_SCALE (hi only) + pack Wout (hi/lo) ----
// grid 768 x 256 = 196608 threads = N_*3 exactly (zeroing) = Wh frag count.
// Wh 16x16x32 B-frag order: value(t,j) = REV*Wh[el][kb*32+quad*8+j][nb*16+l15]
__global__ void prep_k(const float* __restrict__ Wh,
                       const float* __restrict__ Wout,
                       __bf16* __restrict__ Pwh,
                       __bf16* __restrict__ Pwo_hi,
                       __bf16* __restrict__ Pwo_lo,
                       float* __restrict__ out) {
  const int t = blockIdx.x * 256 + threadIdx.x;
  out[t] = 0.0f;                                  // N_*3 == 196608 == grid*block
  const int lane = t & 63;
  const int r = t >> 6;            // [0, 3072)
  const int nb = r & 15;
  const int kb = (r >> 4) & 7;
  const int el = r >> 7;           // [0, 24) = e*3+l
  const int n  = nb * 16 + (lane & 15);
  const int k0 = kb * 32 + (lane >> 4) * 8;
  const float* src = Wh + (size_t)el * (H_ * H_);
  __bf16* dhi = Pwh + (size_t)t * 8;
#pragma unroll
  for (int j = 0; j < 8; ++j)
    dhi[j] = (__bf16)(src[(size_t)(k0 + j) * H_ + n] * REV_SCALE);

  // Wout pack (UNscaled — final layer linear), 16x16x32 layout, t < 4096
  if (t < E_ * 8 * 64) {
    const int kb2 = (t >> 6) & 7;
    const int e   = t >> 9;
    const int n2  = lane & 15;
    const int k02 = kb2 * 32 + (lane >> 4) * 8;
    __bf16* dh = Pwo_hi + (size_t)t * 8;
    __bf16* dl = Pwo_lo + (size_t)t * 8;
#pragma unroll
    for (int j = 0; j < 8; ++j) {
      float v = (n2 < 3) ? Wout[((size_t)e * H_ + (k02 + j)) * 3 + n2] : 0.0f;
      __bf16 hi, lo;
      split_bf16(v, hi, lo);
      dh[j] = hi; dl[j] = lo;
    }
  }
}

// ---- fused MoE-SIREN, PACKED path, MT=64, single-MFMA hidden layers ----
// R18 structure (best verified: 231us), minus fract (R21), plus B ping-pong.
__global__ __launch_bounds__(256, 4) void moe_main_packed_k(
    const float* __restrict__ x,
    const float* __restrict__ gate_W,
    const float* __restrict__ gate_b,
    const float* __restrict__ W0,
    const float* __restrict__ b0,
    const __bf16* __restrict__ Pwh_hi,
    const float* __restrict__ bh,
    const __bf16* __restrict__ Pwo_hi,
    const __bf16* __restrict__ Pwo_lo,
    const float* __restrict__ bout,
    float* __restrict__ out)
{
  __shared__ alignas(16) __bf16 h_hi[MT * HPAD];   // 33792 B
  __shared__ float gate_s[MT];                     // total ~34 KB -> 4 blocks/CU

  const int e    = blockIdx.y;
  const int m0   = blockIdx.x * MT;
  const int tid  = threadIdx.x;
  const int wave = tid >> 6;
  const int lane = tid & 63;
  const int l15  = lane & 15;
  const int quad = lane >> 4;

  // gate for this expert, one row per thread (fp32, matches jax softmax)
  if (tid < MT) {
    const int mg = m0 + tid;
    const float x0 = x[mg * 2 + 0];
    const float x1 = x[mg * 2 + 1];
    float lg[E_];
    float mx = -1e30f;
#pragma unroll
    for (int k = 0; k < E_; ++k) {
      lg[k] = x0 * gate_W[k] + x1 * gate_W[E_ + k] + gate_b[k];
      mx = fmaxf(mx, lg[k]);
    }
    float s = 0.0f;
#pragma unroll
    for (int k = 0; k < E_; ++k) s += __expf(lg[k] - mx);
    gate_s[tid] = __expf(lg[e] - mx) / s;
  }

  const int nb0 = wave * 4;
  const size_t fragoff = (size_t)(nb0 * 64 + lane) * 8;   // wave-invariant frag offset

  // B-fragment running pointer over the 3 contiguous layers of this expert;
  // preload kb=0 of layer 0 NOW so it flies under the first-sine phase.
  const __bf16* pBh = Pwh_hi + (size_t)(e * NHID_) * (8 * 16 * 64 * 8) + fragoff;
  bf16x8 bA[4], bB[4];
#pragma unroll
  for (int nbi = 0; nbi < 4; ++nbi)
    bA[nbi] = *reinterpret_cast<const bf16x8*>(pBh + nbi * 512);
  pBh += 16 * 64 * 8;

  // first sine layer fp32, omega/2pi folded; thread tid owns column n=tid, all 64 rows
  {
    const float w0a = W0[(e * 2 + 0) * H_ + tid] * REV_SCALE;
    const float w1a = W0[(e * 2 + 1) * H_ + tid] * REV_SCALE;
    const float bb  = b0[e * H_ + tid] * REV_SCALE;
    for (int m = 0; m < MT; ++m) {
      const float x0 = x[(m0 + m) * 2 + 0];
      const float x1 = x[(m0 + m) * 2 + 1];
      const float z_rev = fmaf(x1, w1a, fmaf(x0, w0a, bb));
      sin_store(z_rev, h_hi, m * HPAD + tid);
    }
  }
  __syncthreads();

#pragma unroll 1
  for (int l = 0; l < NHID_; ++l) {
    const float* bhrow = bh + (size_t)(e * NHID_ + l) * H_;

    // bias folded into acc init (C/D col = lane-only -> one bias per nbi, all 16 regs)
    float bias_rev[4];
#pragma unroll
    for (int nbi = 0; nbi < 4; ++nbi)
      bias_rev[nbi] = bhrow[(nb0 + nbi) * 16 + l15] * REV_SCALE;

    f32x4 acc[4][4];
#pragma unroll
    for (int mt = 0; mt < 4; ++mt)
#pragma unroll
      for (int nbi = 0; nbi < 4; ++nbi)
        acc[mt][nbi] = (f32x4){bias_rev[nbi], bias_rev[nbi], bias_rev[nbi], bias_rev[nbi]};

    // ping-pong: bA holds B(2*kb2); bB(2*kb2+1) issued before MFMA-block(2*kb2);
    // bA(2*kb2+2) [or next layer's kb0] issued between the two MFMA half-blocks.
#pragma unroll 1
    for (int kb2 = 0; kb2 < 4; ++kb2) {
      const int kb = kb2 * 2;
#pragma unroll
      for (int nbi = 0; nbi < 4; ++nbi)
        bB[nbi] = *reinterpret_cast<const bf16x8*>(pBh + nbi * 512);
      pBh += 16 * 64 * 8;
      {
        const int k0 = kb * 32 + quad * 8;
        bf16x8 ah[4];
#pragma unroll
        for (int mt = 0; mt < 4; ++mt)
          ah[mt] = *reinterpret_cast<const bf16x8*>(&h_hi[(mt * 16 + l15) * HPAD + k0]);
#pragma unroll
        for (int mt = 0; mt < 4; ++mt)
#pragma unroll
          for (int nbi = 0; nbi < 4; ++nbi)
            acc[mt][nbi] = __builtin_amdgcn_mfma_f32_16x16x32_bf16(
                ah[mt], bA[nbi], acc[mt][nbi], 0, 0, 0);
      }
      if (kb2 < 3 || l < NHID_ - 1) {   // last layer, last pair: nothing to fetch
#pragma unroll
        for (int nbi = 0; nbi < 4; ++nbi)
          bA[nbi] = *reinterpret_cast<const bf16x8*>(pBh + nbi * 512);
        pBh += 16 * 64 * 8;
      }
      {
        const int k0 = (kb + 1) * 32 + quad * 8;
        bf16x8 ah[4];
#pragma unroll
        for (int mt = 0; mt < 4; ++mt)
          ah[mt] = *reinterpret_cast<const bf16x8*>(&h_hi[(mt * 16 + l15) * HPAD + k0]);
#pragma unroll
        for (int mt = 0; mt < 4; ++mt)
#pragma unroll
          for (int nbi = 0; nbi < 4; ++nbi)
            acc[mt][nbi] = __builtin_amdgcn_mfma_f32_16x16x32_bf16(
                ah[mt], bB[nbi], acc[mt][nbi], 0, 0, 0);
      }
    }
    // NOTE: at this point bA already holds next layer's kb0 B-frags (global
    // loads in flight across the barrier — the VALU epilogue hides them).
    __syncthreads();

#pragma unroll
    for (int nbi = 0; nbi < 4; ++nbi) {
      const int n = (nb0 + nbi) * 16 + l15;
#pragma unroll
      for (int mt = 0; mt < 4; ++mt) {
        const int rbase = mt * 16 + quad * 4;
#pragma unroll
        for (int i = 0; i < 4; ++i)
          sin_store(acc[mt][nbi][i], h_hi, (rbase + i) * HPAD + n);
      }
    }
    __syncthreads();
  }

  // output layer (linear): 2-term kept (only 16 MFMAs/wave — free accuracy)
  {
    const __bf16* pOh = Pwo_hi + (size_t)e * (8 * 64 * 8) + (size_t)lane * 8;
    const __bf16* pOl = Pwo_lo + (size_t)e * (8 * 64 * 8) + (size_t)lane * 8;
    f32x4 acco = (f32x4){0.f, 0.f, 0.f, 0.f};
    const int arow = wave * 16 + l15;
#pragma unroll 1
    for (int kb = 0; kb < 8; ++kb) {
      bf16x8 bhf = *reinterpret_cast<const bf16x8*>(pOh);
      bf16x8 blf = *reinterpret_cast<const bf16x8*>(pOl);
      pOh += 512; pOl += 512;
      const int k0 = kb * 32 + quad * 8;
      bf16x8 ah = *reinterpret_cast<const bf16x8*>(&h_hi[arow * HPAD + k0]);
      acco = __builtin_amdgcn_mfma_f32_16x16x32_bf16(ah, blf, acco, 0, 0, 0);
      acco = __builtin_amdgcn_mfma_f32_16x16x32_bf16(ah, bhf, acco, 0, 0, 0);
    }
    if (l15 < 3) {
      const float bo = bout[e * 3 + l15];
      const int rb = wave * 16 + quad * 4;
#pragma unroll
      for (int i = 0; i < 4; ++i) {
        const int m = rb + i;
        const float val = gate_s[m] * (acco[i] + bo);
        atomicAdd(&out[(size_t)(m0 + m) * 3 + l15], val);
      }
    }
  }
}

// ---- fallback: direct fp32-weight path (HW-verified round 3, MT=64, 3-term) ----
__global__ __launch_bounds__(256) void moe_main_direct_k(
    const float* __restrict__ x,
    const float* __restrict__ gate_W,
    const float* __restrict__ gate_b,
    const float* __restrict__ W0,
    const float* __restrict__ b0,
    const float* __restrict__ Wh,
    const float* __restrict__ bh,
    const float* __restrict__ Wout,
    const float* __restrict__ bout,
    float* __restrict__ out)
{
  __shared__ alignas(16) __bf16 h_hi[MT * HPAD];
  __shared__ alignas(16) __bf16 h_lo[MT * HPAD];
  __shared__ float gate_s[MT];

  const int e    = blockIdx.y;
  const int m0   = blockIdx.x * MT;
  const int tid  = threadIdx.x;
  const int wave = tid >> 6;
  const int lane = tid & 63;
  const int l15  = lane & 15;
  const int quad = lane >> 4;

  if (tid < MT) {
    const int mg = m0 + tid;
    const float x0 = x[mg * 2 + 0];
    const float x1 = x[mg * 2 + 1];
    float lg[E_];
    float mx = -1e30f;
#pragma unroll
    for (int k = 0; k < E_; ++k) {
      lg[k] = x0 * gate_W[k] + x1 * gate_W[E_ + k] + gate_b[k];
      mx = fmaxf(mx, lg[k]);
    }
    float s = 0.0f;
#pragma unroll
    for (int k = 0; k < E_; ++k) s += __expf(lg[k] - mx);
    gate_s[tid] = __expf(lg[e] - mx) / s;
  }
  {
    const float w0a = W0[(e * 2 + 0) * H_ + tid];
    const float w1a = W0[(e * 2 + 1) * H_ + tid];
    const float bb  = b0[e * H_ + tid];
    for (int m = 0; m < MT; ++m) {
      const float x0 = x[(m0 + m) * 2 + 0];
      const float x1 = x[(m0 + m) * 2 + 1];
      const float z = OMEGA_ * fmaf(x1, w1a, fmaf(x0, w0a, bb));
      const float h = __sinf(z);
      __bf16 hi, lo; split_bf16(h, hi, lo);
      h_hi[m * HPAD + tid] = hi;
      h_lo[m * HPAD + tid] = lo;
    }
  }
  __syncthreads();

  const int nb0 = wave * 4;
#pragma unroll 1
  for (int l = 0; l < NHID_; ++l) {
    const float* WB = Wh + (size_t)(e * NHID_ + l) * (H_ * H_);
    f32x4 acc[4][4];
#pragma unroll
    for (int mt = 0; mt < 4; ++mt)
#pragma unroll
      for (int nbi = 0; nbi < 4; ++nbi)
        acc[mt][nbi] = (f32x4){0.f, 0.f, 0.f, 0.f};

#pragma unroll 2
    for (int kb = 0; kb < 8; ++kb) {
      const int k0 = kb * 32 + quad * 8;
      float bfv[4][8];
#pragma unroll
      for (int nbi = 0; nbi < 4; ++nbi) {
        const float* p = WB + (size_t)k0 * H_ + (nb0 + nbi) * 16 + l15;
#pragma unroll
        for (int j = 0; j < 8; ++j) bfv[nbi][j] = p[(size_t)j * H_];
      }
      bf16x8 ah[4], al[4];
#pragma unroll
      for (int mt = 0; mt < 4; ++mt) {
        ah[mt] = *reinterpret_cast<const bf16x8*>(&h_hi[(mt * 16 + l15) * HPAD + k0]);
        al[mt] = *reinterpret_cast<const bf16x8*>(&h_lo[(mt * 16 + l15) * HPAD + k0]);
      }
      bf16x8 bhf[4], blf[4];
#pragma unroll
      for (int nbi = 0; nbi < 4; ++nbi)
#pragma unroll
        for (int j = 0; j < 8; ++j) {
          __bf16 hi, lo; split_bf16(bfv[nbi][j], hi, lo);
          bhf[nbi][j] = hi; blf[nbi][j] = lo;
        }
#pragma unroll
      for (int mt = 0; mt < 4; ++mt)
#pragma unroll
        for (int nbi = 0; nbi < 4; ++nbi) {
          f32x4 a = acc[mt][nbi];
          a = __builtin_amdgcn_mfma_f32_16x16x32_bf16(al[mt], bhf[nbi], a, 0, 0, 0);
          a = __builtin_amdgcn_mfma_f32_16x16x32_bf16(ah[mt], blf[nbi], a, 0, 0, 0);
          a = __builtin_amdgcn_mfma_f32_16x16x32_bf16(ah[mt], bhf[nbi], a, 0, 0, 0);
          acc[mt][nbi] = a;
        }
    }
    __syncthreads();

    const float* bhrow = bh + (size_t)(e * NHID_ + l) * H_;
#pragma unroll
    for (int nbi = 0; nbi < 4; ++nbi) {
      const int n = (nb0 + nbi) * 16 + l15;
      const float bias = bhrow[n];
#pragma unroll
      for (int mt = 0; mt < 4; ++mt) {
        const int rbase = mt * 16 + quad * 4;
#pragma unroll
        for (int i = 0; i < 4; ++i) {
          const float z = OMEGA_ * (acc[mt][nbi][i] + bias);
          const float h = __sinf(z);
          __bf16 hi, lo; split_bf16(h, hi, lo);
          h_hi[(rbase + i) * HPAD + n] = hi;
          h_lo[(rbase + i) * HPAD + n] = lo;
        }
      }
    }
    __syncthreads();
  }

  {
    const float* WO = Wout + (size_t)e * (H_ * 3);
    f32x4 acco = (f32x4){0.f, 0.f, 0.f, 0.f};
    const int arow = wave * 16 + l15;
#pragma unroll
    for (int kb = 0; kb < 8; ++kb) {
      const int k0 = kb * 32 + quad * 8;
      float bfv[8];
#pragma unroll
      for (int j = 0; j < 8; ++j)
        bfv[j] = (l15 < 3) ? WO[(size_t)(k0 + j) * 3 + l15] : 0.0f;
      bf16x8 ah = *reinterpret_cast<const bf16x8*>(&h_hi[arow * HPAD + k0]);
      bf16x8 al = *reinterpret_cast<const bf16x8*>(&h_lo[arow * HPAD + k0]);
      bf16x8 bhf, blf;
#pragma unroll
      for (int j = 0; j < 8; ++j) {
        __bf16 hi, lo; split_bf16(bfv[j], hi, lo);
        bhf[j] = hi; blf[j] = lo;
      }
      acco = __builtin_amdgcn_mfma_f32_16x16x32_bf16(al, bhf, acco, 0, 0, 0);
      acco = __builtin_amdgcn_mfma_f32_16x16x32_bf16(ah, blf, acco, 0, 0, 0);
      acco = __builtin_amdgcn_mfma_f32_16x16x32_bf16(ah, bhf, acco, 0, 0, 0);
    }
    if (l15 < 3) {
      const float bo = bout[e * 3 + l15];
      const int rb = wave * 16 + quad * 4;
#pragma unroll
      for (int i = 0; i < 4; ++i) {
        const int m = rb + i;
        const float val = gate_s[m] * (acco[i] + bo);
        atomicAdd(&out[(size_t)(m0 + m) * 3 + l15], val);
      }
    }
  }
}

extern "C" void kernel_launch(void* const* d_in, const int* in_sizes, int n_in,
                              void* d_out, int out_size, void* d_ws, size_t ws_size,
                              hipStream_t stream) {
  const float* x     = (const float*)d_in[0];
  const float* gateW = (const float*)d_in[1];
  const float* gateb = (const float*)d_in[2];
  const float* W0    = (const float*)d_in[3];
  const float* b0    = (const float*)d_in[4];
  const float* Wh    = (const float*)d_in[5];
  const float* bh    = (const float*)d_in[6];
  const float* Wout  = (const float*)d_in[7];
  const float* bout  = (const float*)d_in[8];
  float* out = (float*)d_out;

  if (ws_size >= WS_NEEDED) {
    __bf16* Pwh_hi = (__bf16*)d_ws;
    __bf16* Pwo_hi = (__bf16*)((char*)d_ws + (size_t)PWH_ELEMS * 2);
    __bf16* Pwo_lo = (__bf16*)((char*)d_ws + (size_t)PWH_ELEMS * 2 + (size_t)PWO_ELEMS * 2);
    hipLaunchKernelGGL(prep_k, dim3(768), dim3(256), 0, stream,
                       Wh, Wout, Pwh_hi, Pwo_hi, Pwo_lo, out);
    hipLaunchKernelGGL(moe_main_packed_k, dim3(N_ / MT, E_), dim3(256), 0, stream,
                       x, gateW, gateb, W0, b0, Pwh_hi, bh, Pwo_hi, Pwo_lo, bout, out);
  } else {
    hipLaunchKernelGGL(zero_out_k, dim3(N_ * 3 / 256), dim3(256), 0, stream, out);
    hipLaunchKernelGGL(moe_main_direct_k, dim3(N_ / MT, E_), dim3(256), 0, stream,
                       x, gateW, gateb, W0, b0, Wh, bh, Wout, bout, out);
  }
}

// Round 6
// 275.108 us; speedup vs baseline: 1.0479x; 1.0201x over previous
//
#include <hip/hip_runtime.h>
#include <math.h>

#define E_ 8
#define H_ 256
#define N_ 65536
#define NHID_ 3
#define MT 64          // tile: N/64 = 1024 exact
#define HPAD 264       // LDS row stride (bf16 elems): row stride 528B
#define OMEGA_ 30.0f
#define REV_SCALE 4.7746482927568605f   // OMEGA/(2*pi): sin(OMEGA*z) = sin(2pi*(REV_SCALE*z))

// R24 = R23 + MFMA OPERAND SWAP: hidden layers compute D = mfma(W_frag, h_frag)
// (i.e. out^T = W^T * h^T). 16x16x32 A- and B-frags have the IDENTICAL lane
// mapping (idx=l15, k=quad*8+j), so the packed weights and the h ds_read_b128
// are unchanged — but C/D now gives each lane col m=l15 FIXED and 4 CONSECUTIVE
// n per tile (n = (nb0+nbi)*16 + quad*4 + i). Epilogue per tile: 4 sin + one
// ds_write_b64 (was 4 scalar b16 stores + 4 addr calcs). Stores/addr 64->16
// per thread per layer; store bank pattern becomes exact 2-lanes/bank (free).
// Bias folding becomes an aligned f32x4 row-load. Bit-identical numerics.
// R23's B ping-pong prefetch kept (verified +6us).
// ws layout: Pwh_hi | Pwo_hi | Pwo_lo
#define PWH_ELEMS (E_ * NHID_ * 8 * 16 * 64 * 8)   // 1572864 bf16 = 3145728 B
#define PWO_ELEMS (E_ * 8 * 64 * 8)                // 32768 bf16 = 65536 B
#define WS_NEEDED ((size_t)PWH_ELEMS * 2 + 2 * (size_t)PWO_ELEMS * 2)  // 3276800 B

typedef __attribute__((ext_vector_type(8))) __bf16 bf16x8;
typedef __attribute__((ext_vector_type(4))) __bf16 bf16x4;
typedef __attribute__((ext_vector_type(4))) float f32x4;

// RNE split (pack + fallback path)
__device__ __forceinline__ void split_bf16(float v, __bf16& hi, __bf16& lo) {
  hi = (__bf16)v;
  lo = (__bf16)(v - (float)hi);
}

// hot-path: sin + RNE-bf16 + single LDS store. NO fract: inputs bounded |z|<=8.2
// revolutions, inside v_sin_f32's valid +-256 range (HW reduces internally).
__device__ __forceinline__ void sin_store(float z_rev, __bf16* h_hi, int idx) {
  const float s = __builtin_amdgcn_sinf(z_rev);   // sin(2*pi*z_rev)
  h_hi[idx] = (__bf16)s;   // RNE
}

// ---- zero d_out (fallback path only) ----
__global__ void zero_out_k(float* __restrict__ out) {
  out[blockIdx.x * 256 + threadIdx.x] = 0.0f;   // grid exactly N_*3/256
}

// ---- fused prep: zero out + pack Wh*REV_SCALE (hi only) + pack Wout (hi/lo) ----
// grid 768 x 256 = 196608 threads = N_*3 exactly (zeroing) = Wh frag count.
// Wh frag order (unchanged by operand swap — A/B lane maps identical):
//   value(t,j) = REV*Wh[el][kb*32+quad*8+j][nb*16+l15]
__global__ void prep_k(const float* __restrict__ Wh,
                       const float* __restrict__ Wout,
                       __bf16* __restrict__ Pwh,
                       __bf16* __restrict__ Pwo_hi,
                       __bf16* __restrict__ Pwo_lo,
                       float* __restrict__ out) {
  const int t = blockIdx.x * 256 + threadIdx.x;
  out[t] = 0.0f;                                  // N_*3 == 196608 == grid*block
  const int lane = t & 63;
  const int r = t >> 6;            // [0, 3072)
  const int nb = r & 15;
  const int kb = (r >> 4) & 7;
  const int el = r >> 7;           // [0, 24) = e*3+l
  const int n  = nb * 16 + (lane & 15);
  const int k0 = kb * 32 + (lane >> 4) * 8;
  const float* src = Wh + (size_t)el * (H_ * H_);
  __bf16* dhi = Pwh + (size_t)t * 8;
#pragma unroll
  for (int j = 0; j < 8; ++j)
    dhi[j] = (__bf16)(src[(size_t)(k0 + j) * H_ + n] * REV_SCALE);

  // Wout pack (UNscaled — final layer linear), 16x16x32 layout, t < 4096
  if (t < E_ * 8 * 64) {
    const int kb2 = (t >> 6) & 7;
    const int e   = t >> 9;
    const int n2  = lane & 15;
    const int k02 = kb2 * 32 + (lane >> 4) * 8;
    __bf16* dh = Pwo_hi + (size_t)t * 8;
    __bf16* dl = Pwo_lo + (size_t)t * 8;
#pragma unroll
    for (int j = 0; j < 8; ++j) {
      float v = (n2 < 3) ? Wout[((size_t)e * H_ + (k02 + j)) * 3 + n2] : 0.0f;
      __bf16 hi, lo;
      split_bf16(v, hi, lo);
      dh[j] = hi; dl[j] = lo;
    }
  }
}

// ---- fused MoE-SIREN, PACKED path, MT=64, single-MFMA hidden layers ----
// R18 structure minus fract (R21), plus B ping-pong (R23), plus operand swap.
__global__ __launch_bounds__(256, 4) void moe_main_packed_k(
    const float* __restrict__ x,
    const float* __restrict__ gate_W,
    const float* __restrict__ gate_b,
    const float* __restrict__ W0,
    const float* __restrict__ b0,
    const __bf16* __restrict__ Pwh_hi,
    const float* __restrict__ bh,
    const __bf16* __restrict__ Pwo_hi,
    const __bf16* __restrict__ Pwo_lo,
    const float* __restrict__ bout,
    float* __restrict__ out)
{
  __shared__ alignas(16) __bf16 h_hi[MT * HPAD];   // 33792 B
  __shared__ float gate_s[MT];                     // total ~34 KB -> 4 blocks/CU

  const int e    = blockIdx.y;
  const int m0   = blockIdx.x * MT;
  const int tid  = threadIdx.x;
  const int wave = tid >> 6;
  const int lane = tid & 63;
  const int l15  = lane & 15;
  const int quad = lane >> 4;

  // gate for this expert, one row per thread (fp32, matches jax softmax)
  if (tid < MT) {
    const int mg = m0 + tid;
    const float x0 = x[mg * 2 + 0];
    const float x1 = x[mg * 2 + 1];
    float lg[E_];
    float mx = -1e30f;
#pragma unroll
    for (int k = 0; k < E_; ++k) {
      lg[k] = x0 * gate_W[k] + x1 * gate_W[E_ + k] + gate_b[k];
      mx = fmaxf(mx, lg[k]);
    }
    float s = 0.0f;
#pragma unroll
    for (int k = 0; k < E_; ++k) s += __expf(lg[k] - mx);
    gate_s[tid] = __expf(lg[e] - mx) / s;
  }

  const int nb0 = wave * 4;
  const size_t fragoff = (size_t)(nb0 * 64 + lane) * 8;   // wave-invariant frag offset

  // W-fragment running pointer over the 3 contiguous layers of this expert;
  // preload kb=0 of layer 0 NOW so it flies under the first-sine phase.
  const __bf16* pBh = Pwh_hi + (size_t)(e * NHID_) * (8 * 16 * 64 * 8) + fragoff;
  bf16x8 bA[4], bB[4];
#pragma unroll
  for (int nbi = 0; nbi < 4; ++nbi)
    bA[nbi] = *reinterpret_cast<const bf16x8*>(pBh + nbi * 512);
  pBh += 16 * 64 * 8;

  // first sine layer fp32, omega/2pi folded; thread tid owns column n=tid, all 64 rows
  {
    const float w0a = W0[(e * 2 + 0) * H_ + tid] * REV_SCALE;
    const float w1a = W0[(e * 2 + 1) * H_ + tid] * REV_SCALE;
    const float bb  = b0[e * H_ + tid] * REV_SCALE;
    for (int m = 0; m < MT; ++m) {
      const float x0 = x[(m0 + m) * 2 + 0];
      const float x1 = x[(m0 + m) * 2 + 1];
      const float z_rev = fmaf(x1, w1a, fmaf(x0, w0a, bb));
      sin_store(z_rev, h_hi, m * HPAD + tid);
    }
  }
  __syncthreads();

#pragma unroll 1
  for (int l = 0; l < NHID_; ++l) {
    const float* bhrow = bh + (size_t)(e * NHID_ + l) * H_;

    // bias folded into acc init. With swapped operands, D reg i has
    // n = (nb0+nbi)*16 + quad*4 + i -> one aligned f32x4 bias load per nbi.
    f32x4 biasv[4];
#pragma unroll
    for (int nbi = 0; nbi < 4; ++nbi) {
      f32x4 b = *reinterpret_cast<const f32x4*>(bhrow + (nb0 + nbi) * 16 + quad * 4);
      biasv[nbi] = b * REV_SCALE;
    }

    f32x4 acc[4][4];
#pragma unroll
    for (int mt = 0; mt < 4; ++mt)
#pragma unroll
      for (int nbi = 0; nbi < 4; ++nbi)
        acc[mt][nbi] = biasv[nbi];

    // ping-pong: bA holds W(2*kb2); bB(2*kb2+1) issued before MFMA-block(2*kb2);
    // bA(2*kb2+2) [or next layer's kb0] issued between the two MFMA half-blocks.
#pragma unroll 1
    for (int kb2 = 0; kb2 < 4; ++kb2) {
      const int kb = kb2 * 2;
#pragma unroll
      for (int nbi = 0; nbi < 4; ++nbi)
        bB[nbi] = *reinterpret_cast<const bf16x8*>(pBh + nbi * 512);
      pBh += 16 * 64 * 8;
      {
        const int k0 = kb * 32 + quad * 8;
        bf16x8 ah[4];
#pragma unroll
        for (int mt = 0; mt < 4; ++mt)
          ah[mt] = *reinterpret_cast<const bf16x8*>(&h_hi[(mt * 16 + l15) * HPAD + k0]);
#pragma unroll
        for (int mt = 0; mt < 4; ++mt)
#pragma unroll
          for (int nbi = 0; nbi < 4; ++nbi)
            acc[mt][nbi] = __builtin_amdgcn_mfma_f32_16x16x32_bf16(
                bA[nbi], ah[mt], acc[mt][nbi], 0, 0, 0);   // SWAPPED: W first
      }
      if (kb2 < 3 || l < NHID_ - 1) {   // last layer, last pair: nothing to fetch
#pragma unroll
        for (int nbi = 0; nbi < 4; ++nbi)
          bA[nbi] = *reinterpret_cast<const bf16x8*>(pBh + nbi * 512);
        pBh += 16 * 64 * 8;
      }
      {
        const int k0 = (kb + 1) * 32 + quad * 8;
        bf16x8 ah[4];
#pragma unroll
        for (int mt = 0; mt < 4; ++mt)
          ah[mt] = *reinterpret_cast<const bf16x8*>(&h_hi[(mt * 16 + l15) * HPAD + k0]);
#pragma unroll
        for (int mt = 0; mt < 4; ++mt)
#pragma unroll
          for (int nbi = 0; nbi < 4; ++nbi)
            acc[mt][nbi] = __builtin_amdgcn_mfma_f32_16x16x32_bf16(
                bB[nbi], ah[mt], acc[mt][nbi], 0, 0, 0);   // SWAPPED: W first
      }
    }
    // NOTE: at this point bA already holds next layer's kb0 W-frags (global
    // loads in flight across the barrier — the VALU epilogue hides them).
    __syncthreads();

    // epilogue (swapped layout): lane holds row m = mt*16+l15 fixed, 4
    // CONSECUTIVE n per tile -> 4 sin + one ds_write_b64. 16 stores total
    // (was 64 scalar b16). Banks: 4*l15+2*quad+{0,1} covers all 32 banks at
    // exactly 2 lanes/bank -> conflict-free.
#pragma unroll
    for (int mt = 0; mt < 4; ++mt) {
      const int row = mt * 16 + l15;
#pragma unroll
      for (int nbi = 0; nbi < 4; ++nbi) {
        const int n0 = (nb0 + nbi) * 16 + quad * 4;
        bf16x4 v;
#pragma unroll
        for (int i = 0; i < 4; ++i)
          v[i] = (__bf16)__builtin_amdgcn_sinf(acc[mt][nbi][i]);
        *reinterpret_cast<bf16x4*>(&h_hi[row * HPAD + n0]) = v;
      }
    }
    __syncthreads();
  }

  // output layer (linear): 2-term kept (only 16 MFMAs/wave — free accuracy)
  {
    const __bf16* pOh = Pwo_hi + (size_t)e * (8 * 64 * 8) + (size_t)lane * 8;
    const __bf16* pOl = Pwo_lo + (size_t)e * (8 * 64 * 8) + (size_t)lane * 8;
    f32x4 acco = (f32x4){0.f, 0.f, 0.f, 0.f};
    const int arow = wave * 16 + l15;
#pragma unroll 1
    for (int kb = 0; kb < 8; ++kb) {
      bf16x8 bhf = *reinterpret_cast<const bf16x8*>(pOh);
      bf16x8 blf = *reinterpret_cast<const bf16x8*>(pOl);
      pOh += 512; pOl += 512;
      const int k0 = kb * 32 + quad * 8;
      bf16x8 ah = *reinterpret_cast<const bf16x8*>(&h_hi[arow * HPAD + k0]);
      acco = __builtin_amdgcn_mfma_f32_16x16x32_bf16(ah, blf, acco, 0, 0, 0);
      acco = __builtin_amdgcn_mfma_f32_16x16x32_bf16(ah, bhf, acco, 0, 0, 0);
    }
    if (l15 < 3) {
      const float bo = bout[e * 3 + l15];
      const int rb = wave * 16 + quad * 4;
#pragma unroll
      for (int i = 0; i < 4; ++i) {
        const int m = rb + i;
        const float val = gate_s[m] * (acco[i] + bo);
        atomicAdd(&out[(size_t)(m0 + m) * 3 + l15], val);
      }
    }
  }
}

// ---- fallback: direct fp32-weight path (HW-verified round 3, MT=64, 3-term) ----
__global__ __launch_bounds__(256) void moe_main_direct_k(
    const float* __restrict__ x,
    const float* __restrict__ gate_W,
    const float* __restrict__ gate_b,
    const float* __restrict__ W0,
    const float* __restrict__ b0,
    const float* __restrict__ Wh,
    const float* __restrict__ bh,
    const float* __restrict__ Wout,
    const float* __restrict__ bout,
    float* __restrict__ out)
{
  __shared__ alignas(16) __bf16 h_hi[MT * HPAD];
  __shared__ alignas(16) __bf16 h_lo[MT * HPAD];
  __shared__ float gate_s[MT];

  const int e    = blockIdx.y;
  const int m0   = blockIdx.x * MT;
  const int tid  = threadIdx.x;
  const int wave = tid >> 6;
  const int lane = tid & 63;
  const int l15  = lane & 15;
  const int quad = lane >> 4;

  if (tid < MT) {
    const int mg = m0 + tid;
    const float x0 = x[mg * 2 + 0];
    const float x1 = x[mg * 2 + 1];
    float lg[E_];
    float mx = -1e30f;
#pragma unroll
    for (int k = 0; k < E_; ++k) {
      lg[k] = x0 * gate_W[k] + x1 * gate_W[E_ + k] + gate_b[k];
      mx = fmaxf(mx, lg[k]);
    }
    float s = 0.0f;
#pragma unroll
    for (int k = 0; k < E_; ++k) s += __expf(lg[k] - mx);
    gate_s[tid] = __expf(lg[e] - mx) / s;
  }
  {
    const float w0a = W0[(e * 2 + 0) * H_ + tid];
    const float w1a = W0[(e * 2 + 1) * H_ + tid];
    const float bb  = b0[e * H_ + tid];
    for (int m = 0; m < MT; ++m) {
      const float x0 = x[(m0 + m) * 2 + 0];
      const float x1 = x[(m0 + m) * 2 + 1];
      const float z = OMEGA_ * fmaf(x1, w1a, fmaf(x0, w0a, bb));
      const float h = __sinf(z);
      __bf16 hi, lo; split_bf16(h, hi, lo);
      h_hi[m * HPAD + tid] = hi;
      h_lo[m * HPAD + tid] = lo;
    }
  }
  __syncthreads();

  const int nb0 = wave * 4;
#pragma unroll 1
  for (int l = 0; l < NHID_; ++l) {
    const float* WB = Wh + (size_t)(e * NHID_ + l) * (H_ * H_);
    f32x4 acc[4][4];
#pragma unroll
    for (int mt = 0; mt < 4; ++mt)
#pragma unroll
      for (int nbi = 0; nbi < 4; ++nbi)
        acc[mt][nbi] = (f32x4){0.f, 0.f, 0.f, 0.f};

#pragma unroll 2
    for (int kb = 0; kb < 8; ++kb) {
      const int k0 = kb * 32 + quad * 8;
      float bfv[4][8];
#pragma unroll
      for (int nbi = 0; nbi < 4; ++nbi) {
        const float* p = WB + (size_t)k0 * H_ + (nb0 + nbi) * 16 + l15;
#pragma unroll
        for (int j = 0; j < 8; ++j) bfv[nbi][j] = p[(size_t)j * H_];
      }
      bf16x8 ah[4], al[4];
#pragma unroll
      for (int mt = 0; mt < 4; ++mt) {
        ah[mt] = *reinterpret_cast<const bf16x8*>(&h_hi[(mt * 16 + l15) * HPAD + k0]);
        al[mt] = *reinterpret_cast<const bf16x8*>(&h_lo[(mt * 16 + l15) * HPAD + k0]);
      }
      bf16x8 bhf[4], blf[4];
#pragma unroll
      for (int nbi = 0; nbi < 4; ++nbi)
#pragma unroll
        for (int j = 0; j < 8; ++j) {
          __bf16 hi, lo; split_bf16(bfv[nbi][j], hi, lo);
          bhf[nbi][j] = hi; blf[nbi][j] = lo;
        }
#pragma unroll
      for (int mt = 0; mt < 4; ++mt)
#pragma unroll
        for (int nbi = 0; nbi < 4; ++nbi) {
          f32x4 a = acc[mt][nbi];
          a = __builtin_amdgcn_mfma_f32_16x16x32_bf16(al[mt], bhf[nbi], a, 0, 0, 0);
          a = __builtin_amdgcn_mfma_f32_16x16x32_bf16(ah[mt], blf[nbi], a, 0, 0, 0);
          a = __builtin_amdgcn_mfma_f32_16x16x32_bf16(ah[mt], bhf[nbi], a, 0, 0, 0);
          acc[mt][nbi] = a;
        }
    }
    __syncthreads();

    const float* bhrow = bh + (size_t)(e * NHID_ + l) * H_;
#pragma unroll
    for (int nbi = 0; nbi < 4; ++nbi) {
      const int n = (nb0 + nbi) * 16 + l15;
      const float bias = bhrow[n];
#pragma unroll
      for (int mt = 0; mt < 4; ++mt) {
        const int rbase = mt * 16 + quad * 4;
#pragma unroll
        for (int i = 0; i < 4; ++i) {
          const float z = OMEGA_ * (acc[mt][nbi][i] + bias);
          const float h = __sinf(z);
          __bf16 hi, lo; split_bf16(h, hi, lo);
          h_hi[(rbase + i) * HPAD + n] = hi;
          h_lo[(rbase + i) * HPAD + n] = lo;
        }
      }
    }
    __syncthreads();
  }

  {
    const float* WO = Wout + (size_t)e * (H_ * 3);
    f32x4 acco = (f32x4){0.f, 0.f, 0.f, 0.f};
    const int arow = wave * 16 + l15;
#pragma unroll
    for (int kb = 0; kb < 8; ++kb) {
      const int k0 = kb * 32 + quad * 8;
      float bfv[8];
#pragma unroll
      for (int j = 0; j < 8; ++j)
        bfv[j] = (l15 < 3) ? WO[(size_t)(k0 + j) * 3 + l15] : 0.0f;
      bf16x8 ah = *reinterpret_cast<const bf16x8*>(&h_hi[arow * HPAD + k0]);
      bf16x8 al = *reinterpret_cast<const bf16x8*>(&h_lo[arow * HPAD + k0]);
      bf16x8 bhf, blf;
#pragma unroll
      for (int j = 0; j < 8; ++j) {
        __bf16 hi, lo; split_bf16(bfv[j], hi, lo);
        bhf[j] = hi; blf[j] = lo;
      }
      acco = __builtin_amdgcn_mfma_f32_16x16x32_bf16(al, bhf, acco, 0, 0, 0);
      acco = __builtin_amdgcn_mfma_f32_16x16x32_bf16(ah, blf, acco, 0, 0, 0);
      acco = __builtin_amdgcn_mfma_f32_16x16x32_bf16(ah, bhf, acco, 0, 0, 0);
    }
    if (l15 < 3) {
      const float bo = bout[e * 3 + l15];
      const int rb = wave * 16 + quad * 4;
#pragma unroll
      for (int i = 0; i < 4; ++i) {
        const int m = rb + i;
        const float val = gate_s[m] * (acco[i] + bo);
        atomicAdd(&out[(size_t)(m0 + m) * 3 + l15], val);
      }
    }
  }
}

extern "C" void kernel_launch(void* const* d_in, const int* in_sizes, int n_in,
                              void* d_out, int out_size, void* d_ws, size_t ws_size,
                              hipStream_t stream) {
  const float* x     = (const float*)d_in[0];
  const float* gateW = (const float*)d_in[1];
  const float* gateb = (const float*)d_in[2];
  const float* W0    = (const float*)d_in[3];
  const float* b0    = (const float*)d_in[4];
  const float* Wh    = (const float*)d_in[5];
  const float* bh    = (const float*)d_in[6];
  const float* Wout  = (const float*)d_in[7];
  const float* bout  = (const float*)d_in[8];
  float* out = (float*)d_out;

  if (ws_size >= WS_NEEDED) {
    __bf16* Pwh_hi = (__bf16*)d_ws;
    __bf16* Pwo_hi = (__bf16*)((char*)d_ws + (size_t)PWH_ELEMS * 2);
    __bf16* Pwo_lo = (__bf16*)((char*)d_ws + (size_t)PWH_ELEMS * 2 + (size_t)PWO_ELEMS * 2);
    hipLaunchKernelGGL(prep_k, dim3(768), dim3(256), 0, stream,
                       Wh, Wout, Pwh_hi, Pwo_hi, Pwo_lo, out);
    hipLaunchKernelGGL(moe_main_packed_k, dim3(N_ / MT, E_), dim3(256), 0, stream,
                       x, gateW, gateb, W0, b0, Pwh_hi, bh, Pwo_hi, Pwo_lo, bout, out);
  } else {
    hipLaunchKernelGGL(zero_out_k, dim3(N_ * 3 / 256), dim3(256), 0, stream, out);
    hipLaunchKernelGGL(moe_main_direct_k, dim3(N_ / MT, E_), dim3(256), 0, stream,
                       x, gateW, gateb, W0, b0, Wh, bh, Wout, bout, out);
  }
}